// Round 1
// baseline (4213.643 us; speedup 1.0000x reference)
//
#include <hip/hip_runtime.h>
#include <hip/hip_bf16.h>
#include <math.h>

typedef __bf16 bf16_t;
typedef __bf16 bf16x8 __attribute__((ext_vector_type(8)));
typedef float  f32x4  __attribute__((ext_vector_type(4)));

// ---------------- workspace layout (bytes) ----------------
#define WS_WSP    0        // 1297 f32  : collapsed spatial weight vector
#define WS_AH     5248     // 256 f32   : head weights applied to h_T
#define WS_U527   6272     // 527 f32   : intermediate for seg composition
#define WS_BIAS   8384     // 1 f32     : total scalar bias
#define WS_BIASG  8448     // 1024 f32  : gate bias (b_ih + b_hh)
#define WS_WC     12544    // 327680 bf16 (655360 B): fragment-swizzled [x|h] weights

__device__ __forceinline__ float sigmoidf_fast(float x) {
    return 1.f / (1.f + __expf(-x));
}
__device__ __forceinline__ float tanhf_fast(float x) {
    float ax = fabsf(x);
    float t  = __expf(-2.f * ax);
    float r  = (1.f - t) / (1.f + t);
    return copysignf(r, x);
}

// ---------------- head/spatial weight composition (tiny) ----------------
// out = a . [out5 | h_T] + bias ; out5 = spatial . w_sp' ... fully collapsed.
__global__ void k_head(const float* __restrict__ sl_w, const float* __restrict__ sl_b,
                       const float* __restrict__ st_w, const float* __restrict__ st_b,
                       const float* __restrict__ seg_b,
                       const float* __restrict__ l1_w, const float* __restrict__ l1_b,
                       const float* __restrict__ l2_w, const float* __restrict__ l2_b,
                       const float* __restrict__ l4_w, const float* __restrict__ l4_b,
                       const float* __restrict__ l5_w, const float* __restrict__ l5_b,
                       const float* __restrict__ l6_w, const float* __restrict__ l6_b,
                       const float* __restrict__ l7_w, const float* __restrict__ l7_b,
                       float* __restrict__ wsp, float* __restrict__ ah,
                       float* __restrict__ u527_out, float* __restrict__ bias_out) {
    __shared__ float v2[128], v3[256], aa[384], u256[256], u527[527];
    __shared__ float red[8];
    const int t = threadIdx.x;   // 512 threads

    if (t < 128) { float s = 0.f; for (int i = 0; i < 128; ++i) s += l7_w[i] * l6_w[i*128 + t]; v2[t] = s; }
    __syncthreads();
    if (t < 256) { float s = 0.f; for (int i = 0; i < 128; ++i) s += v2[i] * l5_w[i*256 + t]; v3[t] = s; }
    __syncthreads();
    if (t < 384) { float s = 0.f; for (int i = 0; i < 256; ++i) s += v3[i] * l4_w[i*384 + t]; aa[t] = s; }
    __syncthreads();
    if (t < 256) { float s = 0.f; for (int i = 0; i < 128; ++i) s += aa[i] * l2_w[i*256 + t]; u256[t] = s; }
    if (t < 256) ah[t] = aa[128 + t];
    __syncthreads();
    for (int j = t; j < 527; j += 512) {
        float s = 0.f;
        for (int i = 0; i < 256; ++i) s += u256[i] * l1_w[i*527 + j];
        u527[j] = s; u527_out[j] = s;
    }
    __syncthreads();
    // small w_sp pieces
    if (t < 4)              { float s = 0.f; for (int i = 0; i < 2; ++i) s += u527[i]     * sl_w[i*4  + t];      wsp[t] = s; }
    else if (t < 16)        { int c = t - 4;  float s = 0.f; for (int i = 0; i < 8; ++i) s += u527[2+i] * st_w[i*12 + c]; wsp[t] = s; }
    else if (t < 21)        { wsp[1292 + (t - 16)] = u527[522 + (t - 16)]; }
    // bias: parallel dot of every bias vector with its coefficient vector
    float p = 0.f;
    if (t < 128) p += l7_w[t] * l6_b[t] + v2[t] * l5_b[t] + aa[t] * l2_b[t];
    if (t < 256) p += v3[t] * l4_b[t] + u256[t] * l1_b[t];
    if (t < 2)   p += u527[t] * sl_b[t];
    if (t < 8)   p += u527[2 + t] * st_b[t];
    p += u527[10 + t] * seg_b[t];          // t < 512 covers all 512
    p += __shfl_xor(p, 1);  p += __shfl_xor(p, 2);  p += __shfl_xor(p, 4);
    p += __shfl_xor(p, 8);  p += __shfl_xor(p, 16); p += __shfl_xor(p, 32);
    if ((t & 63) == 0) red[t >> 6] = p;
    __syncthreads();
    if (t == 0) {
        float s = l7_b[0];
        for (int i = 0; i < 8; ++i) s += red[i];
        *bias_out = s;
    }
}

// w_sp[16+j] = sum_i u527[10+i] * seg_w[i][j]
__global__ void k_seg(const float* __restrict__ seg_w, const float* __restrict__ u527,
                      float* __restrict__ wsp) {
    int j = blockIdx.x * 256 + threadIdx.x;
    if (j >= 1276) return;
    float s = 0.f;
    for (int i = 0; i < 512; ++i) s += u527[10 + i] * seg_w[i*1276 + j];
    wsp[16 + j] = s;
}

// Build fragment-swizzled bf16 combined weights Wc and gate bias.
// Logical W: [n=1024][k=320], k<56: w_ih, 56<=k<64: 0 (pad), k>=64: w_hh[k-64].
// Physical: elem for (ntile=n>>4, kk=k>>5) block at ((ntile*10+kk)*64 + lane)*8 + e
// with n = ntile*16 + (lane&15), k = kk*32 + (lane>>4)*8 + e  -> contiguous 1KB wave loads.
__global__ void k_wc(const float* __restrict__ w_ih, const float* __restrict__ b_ih,
                     const float* __restrict__ w_hh, const float* __restrict__ b_hh,
                     bf16_t* __restrict__ wc, float* __restrict__ biasg) {
    int idx = blockIdx.x * 256 + threadIdx.x;
    if (idx < 1024) biasg[idx] = b_ih[idx] + b_hh[idx];
    if (idx < 1024 * 320) {
        int e  = idx & 7;
        int l  = (idx >> 3) & 63;
        int t2 = idx >> 9;
        int kk = t2 % 10;
        int nt = t2 / 10;
        int n  = nt * 16 + (l & 15);
        int k  = kk * 32 + ((l >> 4) << 3) + e;
        float v = 0.f;
        if (k < 56)       v = w_ih[n*56 + k];
        else if (k >= 64) v = w_hh[n*256 + (k - 64)];
        wc[idx] = (bf16_t)v;
    }
}

// out[b] = dot(spatial[b], w_sp) + bias   (one wave per row)
__global__ void k_spatial(const float* __restrict__ sp, const float* __restrict__ wsp,
                          const float* __restrict__ bias, float* __restrict__ out) {
    int row  = blockIdx.x * 4 + (threadIdx.x >> 6);
    int lane = threadIdx.x & 63;
    const float* rp = sp + (size_t)row * 1297;
    float s = 0.f;
    for (int k = lane; k < 1297; k += 64) s += rp[k] * wsp[k];
    s += __shfl_xor(s, 1);  s += __shfl_xor(s, 2);  s += __shfl_xor(s, 4);
    s += __shfl_xor(s, 8);  s += __shfl_xor(s, 16); s += __shfl_xor(s, 32);
    if (lane == 0) out[row] = s + bias[0];
}

// ---------------- LSTM: 256 blocks x 64 rows, 8 waves, bf16 MFMA ----------------
// A-tile (LDS): [64 rows][328 bf16], cols 0..55 = x_t, 56..63 = 0, 64..319 = h.
// Wave w owns hidden dims j in [32w, 32w+32): gate cols {q*256 + 32w + 16u | q=0..3, u=0..1}.
// acc: f32x4[4 rowtiles][4 gates][2 halves] = 128 VGPR; c state 32 VGPR.
__launch_bounds__(512, 2)
__global__ void k_lstm(const float* __restrict__ temporal, const bf16_t* __restrict__ wc,
                       const float* __restrict__ biasg, const float* __restrict__ ah,
                       float* __restrict__ out) {
    __shared__ bf16_t At[64 * 328];
    const int tid  = threadIdx.x;
    const int lane = tid & 63;
    const int wid  = tid >> 6;              // 0..7
    const int row0 = blockIdx.x * 64;
    const int l15  = lane & 15;
    const int l4q  = lane >> 4;             // 0..3

    for (int i = tid; i < 64 * 328; i += 512) At[i] = (bf16_t)0.f;

    f32x4 cst[4][2];
#pragma unroll
    for (int r = 0; r < 4; ++r)
#pragma unroll
        for (int u = 0; u < 2; ++u) cst[r][u] = (f32x4){0.f, 0.f, 0.f, 0.f};

    float bias[4][2];
#pragma unroll
    for (int q = 0; q < 4; ++q)
#pragma unroll
        for (int u = 0; u < 2; ++u)
            bias[q][u] = biasg[q*256 + wid*32 + u*16 + l15];

    const bf16_t* bptr[4][2];
#pragma unroll
    for (int q = 0; q < 4; ++q)
#pragma unroll
        for (int u = 0; u < 2; ++u) {
            int nt = q*16 + wid*2 + u;      // n-tile index
            bptr[q][u] = wc + ((size_t)nt * 640 + lane) * 8;
        }

    int aoff[4];
#pragma unroll
    for (int r = 0; r < 4; ++r) aoff[r] = (16*r + l15) * 328 + l4q * 8;

    const float* xbase = temporal + (size_t)row0 * (96 * 56);

    for (int t = 0; t < 96; ++t) {
        // stage x_t into A cols [0,56)
        for (int i = tid; i < 64 * 56; i += 512) {
            int r = i / 56, c = i - r * 56;
            At[r*328 + c] = (bf16_t)xbase[(size_t)r * (96*56) + t*56 + c];
        }
        __syncthreads();   // x + previous h visible to all

        f32x4 acc[4][4][2];
#pragma unroll
        for (int r = 0; r < 4; ++r)
#pragma unroll
            for (int q = 0; q < 4; ++q)
#pragma unroll
                for (int u = 0; u < 2; ++u) {
                    float b = bias[q][u];
                    acc[r][q][u] = (f32x4){b, b, b, b};
                }

#pragma unroll
        for (int kk = 0; kk < 10; ++kk) {
            bf16x8 af[4];
#pragma unroll
            for (int r = 0; r < 4; ++r)
                af[r] = *reinterpret_cast<const bf16x8*>(&At[aoff[r] + kk*32]);
#pragma unroll
            for (int q = 0; q < 4; ++q)
#pragma unroll
                for (int u = 0; u < 2; ++u) {
                    bf16x8 bfragv = *reinterpret_cast<const bf16x8*>(bptr[q][u] + kk*512);
#pragma unroll
                    for (int r = 0; r < 4; ++r)
                        acc[r][q][u] = __builtin_amdgcn_mfma_f32_16x16x32_bf16(
                            af[r], bfragv, acc[r][q][u], 0, 0, 0);
                }
        }
        __syncthreads();   // all A reads done before h (and next x) overwrite

        // gates -> c,h ; write h (bf16) back into A-tile cols [64,320)
#pragma unroll
        for (int r = 0; r < 4; ++r)
#pragma unroll
            for (int u = 0; u < 2; ++u)
#pragma unroll
                for (int reg = 0; reg < 4; ++reg) {
                    float iv = acc[r][0][u][reg];
                    float fv = acc[r][1][u][reg];
                    float gv = acc[r][2][u][reg];
                    float ov = acc[r][3][u][reg];
                    float ig = sigmoidf_fast(iv);
                    float fg = sigmoidf_fast(fv);
                    float og = sigmoidf_fast(ov);
                    float gt = tanhf_fast(gv);
                    float cn = fg * cst[r][u][reg] + ig * gt;
                    cst[r][u][reg] = cn;
                    float hh = og * tanhf_fast(cn);
                    int rrow = 16*r + (l4q << 2) + reg;
                    int ccol = 64 + wid*32 + u*16 + l15;
                    At[rrow*328 + ccol] = (bf16_t)hh;
                }
    }
    __syncthreads();

    // out[row] += ah . h_T[row]
    {
        int r = tid >> 3, part = tid & 7;
        float s = 0.f;
        for (int j = part*32; j < part*32 + 32; ++j)
            s += ah[j] * (float)At[r*328 + 64 + j];
        s += __shfl_xor(s, 1); s += __shfl_xor(s, 2); s += __shfl_xor(s, 4);
        if (part == 0) out[row0 + r] += s;
    }
}

// ---------------- launch ----------------
extern "C" void kernel_launch(void* const* d_in, const int* in_sizes, int n_in,
                              void* d_out, int out_size, void* d_ws, size_t ws_size,
                              hipStream_t stream) {
    const float* spatial  = (const float*)d_in[0];
    const float* temporal = (const float*)d_in[1];
    const float* sl_w = (const float*)d_in[2];  const float* sl_b = (const float*)d_in[3];
    const float* st_w = (const float*)d_in[4];  const float* st_b = (const float*)d_in[5];
    const float* seg_w = (const float*)d_in[6]; const float* seg_b = (const float*)d_in[7];
    const float* l1_w = (const float*)d_in[8];  const float* l1_b = (const float*)d_in[9];
    const float* l2_w = (const float*)d_in[10]; const float* l2_b = (const float*)d_in[11];
    const float* w_ih = (const float*)d_in[12]; const float* b_ih = (const float*)d_in[13];
    const float* w_hh = (const float*)d_in[14]; const float* b_hh = (const float*)d_in[15];
    const float* l4_w = (const float*)d_in[16]; const float* l4_b = (const float*)d_in[17];
    const float* l5_w = (const float*)d_in[18]; const float* l5_b = (const float*)d_in[19];
    const float* l6_w = (const float*)d_in[20]; const float* l6_b = (const float*)d_in[21];
    const float* l7_w = (const float*)d_in[22]; const float* l7_b = (const float*)d_in[23];

    char* ws = (char*)d_ws;
    float*  wsp   = (float*)(ws + WS_WSP);
    float*  ah    = (float*)(ws + WS_AH);
    float*  u527  = (float*)(ws + WS_U527);
    float*  biasT = (float*)(ws + WS_BIAS);
    float*  biasg = (float*)(ws + WS_BIASG);
    bf16_t* wc    = (bf16_t*)(ws + WS_WC);

    float* out = (float*)d_out;

    hipLaunchKernelGGL(k_head, dim3(1), dim3(512), 0, stream,
                       sl_w, sl_b, st_w, st_b, seg_b, l1_w, l1_b, l2_w, l2_b,
                       l4_w, l4_b, l5_w, l5_b, l6_w, l6_b, l7_w, l7_b,
                       wsp, ah, u527, biasT);
    hipLaunchKernelGGL(k_seg, dim3(5), dim3(256), 0, stream, seg_w, u527, wsp);
    hipLaunchKernelGGL(k_wc, dim3((1024*320 + 255)/256), dim3(256), 0, stream,
                       w_ih, b_ih, w_hh, b_hh, wc, biasg);
    hipLaunchKernelGGL(k_spatial, dim3(16384/4), dim3(256), 0, stream,
                       spatial, wsp, biasT, out);
    hipLaunchKernelGGL(k_lstm, dim3(256), dim3(512), 0, stream,
                       temporal, wc, biasg, ah, out);
}

// Round 2
// 3188.197 us; speedup vs baseline: 1.3216x; 1.3216x over previous
//
#include <hip/hip_runtime.h>
#include <hip/hip_bf16.h>
#include <math.h>

typedef __bf16 bf16_t;
typedef __bf16 bf16x8 __attribute__((ext_vector_type(8)));
typedef float  f32x4  __attribute__((ext_vector_type(4)));

// ---------------- workspace layout (bytes) ----------------
#define WS_WSP    0        // 1297 f32  : collapsed spatial weight vector
#define WS_AH     5248     // 256 f32   : head weights applied to h_T
#define WS_U527   6272     // 527 f32   : intermediate for seg composition
#define WS_BIAS   8384     // 1 f32     : total scalar bias
#define WS_BIASG  8448     // 1024 f32  : gate bias (b_ih + b_hh)
#define WS_WC     12544    // 327680 bf16 (655360 B): fragment-swizzled [x|h] weights

__device__ __forceinline__ float sigmoidf_fast(float x) {
    return 1.f / (1.f + __expf(-x));
}
__device__ __forceinline__ float tanhf_fast(float x) {
    float ax = fabsf(x);
    float t  = __expf(-2.f * ax);
    float r  = (1.f - t) / (1.f + t);
    return copysignf(r, x);
}

// ---------------- head/spatial weight composition (tiny) ----------------
__global__ void k_head(const float* __restrict__ sl_w, const float* __restrict__ sl_b,
                       const float* __restrict__ st_w, const float* __restrict__ st_b,
                       const float* __restrict__ seg_b,
                       const float* __restrict__ l1_w, const float* __restrict__ l1_b,
                       const float* __restrict__ l2_w, const float* __restrict__ l2_b,
                       const float* __restrict__ l4_w, const float* __restrict__ l4_b,
                       const float* __restrict__ l5_w, const float* __restrict__ l5_b,
                       const float* __restrict__ l6_w, const float* __restrict__ l6_b,
                       const float* __restrict__ l7_w, const float* __restrict__ l7_b,
                       float* __restrict__ wsp, float* __restrict__ ah,
                       float* __restrict__ u527_out, float* __restrict__ bias_out) {
    __shared__ float v2[128], v3[256], aa[384], u256[256], u527[527];
    __shared__ float red[8];
    const int t = threadIdx.x;   // 512 threads

    if (t < 128) { float s = 0.f; for (int i = 0; i < 128; ++i) s += l7_w[i] * l6_w[i*128 + t]; v2[t] = s; }
    __syncthreads();
    if (t < 256) { float s = 0.f; for (int i = 0; i < 128; ++i) s += v2[i] * l5_w[i*256 + t]; v3[t] = s; }
    __syncthreads();
    if (t < 384) { float s = 0.f; for (int i = 0; i < 256; ++i) s += v3[i] * l4_w[i*384 + t]; aa[t] = s; }
    __syncthreads();
    if (t < 256) { float s = 0.f; for (int i = 0; i < 128; ++i) s += aa[i] * l2_w[i*256 + t]; u256[t] = s; }
    if (t < 256) ah[t] = aa[128 + t];
    __syncthreads();
    for (int j = t; j < 527; j += 512) {
        float s = 0.f;
        for (int i = 0; i < 256; ++i) s += u256[i] * l1_w[i*527 + j];
        u527[j] = s; u527_out[j] = s;
    }
    __syncthreads();
    if (t < 4)              { float s = 0.f; for (int i = 0; i < 2; ++i) s += u527[i]     * sl_w[i*4  + t];      wsp[t] = s; }
    else if (t < 16)        { int c = t - 4;  float s = 0.f; for (int i = 0; i < 8; ++i) s += u527[2+i] * st_w[i*12 + c]; wsp[t] = s; }
    else if (t < 21)        { wsp[1292 + (t - 16)] = u527[522 + (t - 16)]; }
    float p = 0.f;
    if (t < 128) p += l7_w[t] * l6_b[t] + v2[t] * l5_b[t] + aa[t] * l2_b[t];
    if (t < 256) p += v3[t] * l4_b[t] + u256[t] * l1_b[t];
    if (t < 2)   p += u527[t] * sl_b[t];
    if (t < 8)   p += u527[2 + t] * st_b[t];
    p += u527[10 + t] * seg_b[t];
    p += __shfl_xor(p, 1);  p += __shfl_xor(p, 2);  p += __shfl_xor(p, 4);
    p += __shfl_xor(p, 8);  p += __shfl_xor(p, 16); p += __shfl_xor(p, 32);
    if ((t & 63) == 0) red[t >> 6] = p;
    __syncthreads();
    if (t == 0) {
        float s = l7_b[0];
        for (int i = 0; i < 8; ++i) s += red[i];
        *bias_out = s;
    }
}

__global__ void k_seg(const float* __restrict__ seg_w, const float* __restrict__ u527,
                      float* __restrict__ wsp) {
    int j = blockIdx.x * 256 + threadIdx.x;
    if (j >= 1276) return;
    float s = 0.f;
    for (int i = 0; i < 512; ++i) s += u527[10 + i] * seg_w[i*1276 + j];
    wsp[16 + j] = s;
}

// Build fragment-swizzled bf16 combined weights Wc and gate bias.
// Logical W: [n=1024][k=320], k<56: w_ih, 56<=k<64: 0 (pad), k>=64: w_hh[k-64].
// Physical: elem for (ntile=n>>4, kk=k>>5) at ((ntile*10+kk)*64 + lane)*8 + e
// with n = ntile*16 + (lane&15), k = kk*32 + (lane>>4)*8 + e.
__global__ void k_wc(const float* __restrict__ w_ih, const float* __restrict__ b_ih,
                     const float* __restrict__ w_hh, const float* __restrict__ b_hh,
                     bf16_t* __restrict__ wc, float* __restrict__ biasg) {
    int idx = blockIdx.x * 256 + threadIdx.x;
    if (idx < 1024) biasg[idx] = b_ih[idx] + b_hh[idx];
    if (idx < 1024 * 320) {
        int e  = idx & 7;
        int l  = (idx >> 3) & 63;
        int t2 = idx >> 9;
        int kk = t2 % 10;
        int nt = t2 / 10;
        int n  = nt * 16 + (l & 15);
        int k  = kk * 32 + ((l >> 4) << 3) + e;
        float v = 0.f;
        if (k < 56)       v = w_ih[n*56 + k];
        else if (k >= 64) v = w_hh[n*256 + (k - 64)];
        wc[idx] = (bf16_t)v;
    }
}

// out[b] = dot(spatial[b], w_sp) + bias   (one wave per row)
__global__ void k_spatial(const float* __restrict__ sp, const float* __restrict__ wsp,
                          const float* __restrict__ bias, float* __restrict__ out) {
    int row  = blockIdx.x * 4 + (threadIdx.x >> 6);
    int lane = threadIdx.x & 63;
    const float* rp = sp + (size_t)row * 1297;
    float s = 0.f;
    for (int k = lane; k < 1297; k += 64) s += rp[k] * wsp[k];
    s += __shfl_xor(s, 1);  s += __shfl_xor(s, 2);  s += __shfl_xor(s, 4);
    s += __shfl_xor(s, 8);  s += __shfl_xor(s, 16); s += __shfl_xor(s, 32);
    if (lane == 0) out[row] = s + bias[0];
}

// ---------------- LSTM: weight-stationary, 256 blocks x 64 rows, 16 waves ----------------
// A-tile (LDS): [64 rows][328 bf16], cols 0..55 = x_t, 56..63 = 0, 64..319 = h.
// Wave w owns hidden dims [16w,16w+16) for ALL 4 gates (gate coupling wave-local).
// Weights for the wave's 4 N-tiles x 10 K-frags live in 160 VGPRs for the whole kernel.
__launch_bounds__(1024)
__global__ void k_lstm(const float* __restrict__ temporal, const bf16_t* __restrict__ wc,
                       const float* __restrict__ biasg, const float* __restrict__ ah,
                       float* __restrict__ out) {
    __shared__ bf16_t At[64 * 328];
    const int tid  = threadIdx.x;
    const int lane = tid & 63;
    const int w    = tid >> 6;              // wave 0..15
    const int row0 = blockIdx.x * 64;
    const int l15  = lane & 15;
    const int l4q  = lane >> 4;             // 0..3

    // --- persistent weight fragments: wf[q][kk] for gate q, K-chunk kk ---
    bf16x8 wf[4][10];
#pragma unroll
    for (int q = 0; q < 4; ++q)
#pragma unroll
        for (int kk = 0; kk < 10; ++kk) {
            int ntg = q * 16 + w;           // global n-tile (col q*256 + 16w)
            wf[q][kk] = *reinterpret_cast<const bf16x8*>(
                wc + (((size_t)(ntg * 10 + kk) * 64 + lane) * 8));
        }

    float bias[4];
#pragma unroll
    for (int q = 0; q < 4; ++q) bias[q] = biasg[q*256 + w*16 + l15];

    f32x4 cst[4];
#pragma unroll
    for (int rt = 0; rt < 4; ++rt) cst[rt] = (f32x4){0.f, 0.f, 0.f, 0.f};

    for (int i = tid; i < 64 * 328; i += 1024) At[i] = (bf16_t)0.f;
    __syncthreads();

    int aoff[4];
#pragma unroll
    for (int rt = 0; rt < 4; ++rt) aoff[rt] = (16*rt + l15) * 328 + l4q * 8;

    const float* xbase = temporal + (size_t)row0 * (96 * 56);
    const int hcol = 64 + w*16 + l15;

    for (int t = 0; t < 96; ++t) {
        // stage x_t into A cols [0,56)
        for (int i = tid; i < 64 * 56; i += 1024) {
            int r = i / 56, c = i - r * 56;
            At[r*328 + c] = (bf16_t)xbase[(size_t)r * (96*56) + t*56 + c];
        }
        __syncthreads();   // x + previous h visible to all

        f32x4 acc[4][4];   // [rowtile][gate]
#pragma unroll
        for (int rt = 0; rt < 4; ++rt)
#pragma unroll
            for (int q = 0; q < 4; ++q)
                acc[rt][q] = (f32x4){bias[q], bias[q], bias[q], bias[q]};

#pragma unroll
        for (int kk = 0; kk < 10; ++kk) {
            bf16x8 af[4];
#pragma unroll
            for (int rt = 0; rt < 4; ++rt)
                af[rt] = *reinterpret_cast<const bf16x8*>(&At[aoff[rt] + kk*32]);
#pragma unroll
            for (int q = 0; q < 4; ++q)
#pragma unroll
                for (int rt = 0; rt < 4; ++rt)
                    acc[rt][q] = __builtin_amdgcn_mfma_f32_16x16x32_bf16(
                        af[rt], wf[q][kk], acc[rt][q], 0, 0, 0);
        }
        __syncthreads();   // all A reads done before h (and next x) overwrite

        // gates -> c,h ; write h (bf16) back into A-tile cols [64,320)
#pragma unroll
        for (int rt = 0; rt < 4; ++rt)
#pragma unroll
            for (int reg = 0; reg < 4; ++reg) {
                float ig = sigmoidf_fast(acc[rt][0][reg]);
                float fg = sigmoidf_fast(acc[rt][1][reg]);
                float gt = tanhf_fast(acc[rt][2][reg]);
                float og = sigmoidf_fast(acc[rt][3][reg]);
                float cn = fg * cst[rt][reg] + ig * gt;
                cst[rt][reg] = cn;
                float hh = og * tanhf_fast(cn);
                At[(16*rt + l4q*4 + reg)*328 + hcol] = (bf16_t)hh;
            }
    }
    __syncthreads();

    // out[row] += ah . h_T[row]   (16 threads per row)
    {
        int r = tid >> 4, part = tid & 15;
        float s = 0.f;
#pragma unroll
        for (int j = 0; j < 16; ++j)
            s += ah[part*16 + j] * (float)At[r*328 + 64 + part*16 + j];
        s += __shfl_xor(s, 1); s += __shfl_xor(s, 2);
        s += __shfl_xor(s, 4); s += __shfl_xor(s, 8);
        if (part == 0) out[row0 + r] += s;
    }
}

// ---------------- launch ----------------
extern "C" void kernel_launch(void* const* d_in, const int* in_sizes, int n_in,
                              void* d_out, int out_size, void* d_ws, size_t ws_size,
                              hipStream_t stream) {
    const float* spatial  = (const float*)d_in[0];
    const float* temporal = (const float*)d_in[1];
    const float* sl_w = (const float*)d_in[2];  const float* sl_b = (const float*)d_in[3];
    const float* st_w = (const float*)d_in[4];  const float* st_b = (const float*)d_in[5];
    const float* seg_w = (const float*)d_in[6]; const float* seg_b = (const float*)d_in[7];
    const float* l1_w = (const float*)d_in[8];  const float* l1_b = (const float*)d_in[9];
    const float* l2_w = (const float*)d_in[10]; const float* l2_b = (const float*)d_in[11];
    const float* w_ih = (const float*)d_in[12]; const float* b_ih = (const float*)d_in[13];
    const float* w_hh = (const float*)d_in[14]; const float* b_hh = (const float*)d_in[15];
    const float* l4_w = (const float*)d_in[16]; const float* l4_b = (const float*)d_in[17];
    const float* l5_w = (const float*)d_in[18]; const float* l5_b = (const float*)d_in[19];
    const float* l6_w = (const float*)d_in[20]; const float* l6_b = (const float*)d_in[21];
    const float* l7_w = (const float*)d_in[22]; const float* l7_b = (const float*)d_in[23];

    char* ws = (char*)d_ws;
    float*  wsp   = (float*)(ws + WS_WSP);
    float*  ah    = (float*)(ws + WS_AH);
    float*  u527  = (float*)(ws + WS_U527);
    float*  biasT = (float*)(ws + WS_BIAS);
    float*  biasg = (float*)(ws + WS_BIASG);
    bf16_t* wc    = (bf16_t*)(ws + WS_WC);

    float* out = (float*)d_out;

    hipLaunchKernelGGL(k_head, dim3(1), dim3(512), 0, stream,
                       sl_w, sl_b, st_w, st_b, seg_b, l1_w, l1_b, l2_w, l2_b,
                       l4_w, l4_b, l5_w, l5_b, l6_w, l6_b, l7_w, l7_b,
                       wsp, ah, u527, biasT);
    hipLaunchKernelGGL(k_seg, dim3(5), dim3(256), 0, stream, seg_w, u527, wsp);
    hipLaunchKernelGGL(k_wc, dim3((1024*320 + 255)/256), dim3(256), 0, stream,
                       w_ih, b_ih, w_hh, b_hh, wc, biasg);
    hipLaunchKernelGGL(k_spatial, dim3(16384/4), dim3(256), 0, stream,
                       spatial, wsp, biasT, out);
    hipLaunchKernelGGL(k_lstm, dim3(256), dim3(1024), 0, stream,
                       temporal, wc, biasg, ah, out);
}

// Round 3
// 3167.389 us; speedup vs baseline: 1.3303x; 1.0066x over previous
//
#include <hip/hip_runtime.h>
#include <hip/hip_bf16.h>
#include <math.h>

typedef __bf16 bf16_t;
typedef __bf16 bf16x8 __attribute__((ext_vector_type(8)));
typedef float  f32x4  __attribute__((ext_vector_type(4)));

// ---------------- workspace layout (bytes) ----------------
#define WS_WSP    0        // 1297 f32  : collapsed spatial weight vector
#define WS_AH     5248     // 256 f32   : head weights applied to h_T
#define WS_U527   6272     // 527 f32   : intermediate for seg composition
#define WS_BIAS   8384     // 1 f32     : total scalar bias
#define WS_BIASG  8448     // 1024 f32  : gate bias (b_ih + b_hh)
#define WS_WC     12544    // 327680 bf16 (655360 B): fragment-swizzled [x|h] weights

__device__ __forceinline__ float sigmoidf_fast(float x) {
    return 1.f / (1.f + __expf(-x));
}
__device__ __forceinline__ float tanhf_fast(float x) {
    float ax = fabsf(x);
    float t  = __expf(-2.f * ax);
    float r  = (1.f - t) / (1.f + t);
    return copysignf(r, x);
}

// ---------------- head/spatial weight composition (tiny) ----------------
__global__ void k_head(const float* __restrict__ sl_w, const float* __restrict__ sl_b,
                       const float* __restrict__ st_w, const float* __restrict__ st_b,
                       const float* __restrict__ seg_b,
                       const float* __restrict__ l1_w, const float* __restrict__ l1_b,
                       const float* __restrict__ l2_w, const float* __restrict__ l2_b,
                       const float* __restrict__ l4_w, const float* __restrict__ l4_b,
                       const float* __restrict__ l5_w, const float* __restrict__ l5_b,
                       const float* __restrict__ l6_w, const float* __restrict__ l6_b,
                       const float* __restrict__ l7_w, const float* __restrict__ l7_b,
                       float* __restrict__ wsp, float* __restrict__ ah,
                       float* __restrict__ u527_out, float* __restrict__ bias_out) {
    __shared__ float v2[128], v3[256], aa[384], u256[256], u527[527];
    __shared__ float red[8];
    const int t = threadIdx.x;   // 512 threads

    if (t < 128) { float s = 0.f; for (int i = 0; i < 128; ++i) s += l7_w[i] * l6_w[i*128 + t]; v2[t] = s; }
    __syncthreads();
    if (t < 256) { float s = 0.f; for (int i = 0; i < 128; ++i) s += v2[i] * l5_w[i*256 + t]; v3[t] = s; }
    __syncthreads();
    if (t < 384) { float s = 0.f; for (int i = 0; i < 256; ++i) s += v3[i] * l4_w[i*384 + t]; aa[t] = s; }
    __syncthreads();
    if (t < 256) { float s = 0.f; for (int i = 0; i < 128; ++i) s += aa[i] * l2_w[i*256 + t]; u256[t] = s; }
    if (t < 256) ah[t] = aa[128 + t];
    __syncthreads();
    for (int j = t; j < 527; j += 512) {
        float s = 0.f;
        for (int i = 0; i < 256; ++i) s += u256[i] * l1_w[i*527 + j];
        u527[j] = s; u527_out[j] = s;
    }
    __syncthreads();
    if (t < 4)              { float s = 0.f; for (int i = 0; i < 2; ++i) s += u527[i]     * sl_w[i*4  + t];      wsp[t] = s; }
    else if (t < 16)        { int c = t - 4;  float s = 0.f; for (int i = 0; i < 8; ++i) s += u527[2+i] * st_w[i*12 + c]; wsp[t] = s; }
    else if (t < 21)        { wsp[1292 + (t - 16)] = u527[522 + (t - 16)]; }
    float p = 0.f;
    if (t < 128) p += l7_w[t] * l6_b[t] + v2[t] * l5_b[t] + aa[t] * l2_b[t];
    if (t < 256) p += v3[t] * l4_b[t] + u256[t] * l1_b[t];
    if (t < 2)   p += u527[t] * sl_b[t];
    if (t < 8)   p += u527[2 + t] * st_b[t];
    p += u527[10 + t] * seg_b[t];
    p += __shfl_xor(p, 1);  p += __shfl_xor(p, 2);  p += __shfl_xor(p, 4);
    p += __shfl_xor(p, 8);  p += __shfl_xor(p, 16); p += __shfl_xor(p, 32);
    if ((t & 63) == 0) red[t >> 6] = p;
    __syncthreads();
    if (t == 0) {
        float s = l7_b[0];
        for (int i = 0; i < 8; ++i) s += red[i];
        *bias_out = s;
    }
}

__global__ void k_seg(const float* __restrict__ seg_w, const float* __restrict__ u527,
                      float* __restrict__ wsp) {
    int j = blockIdx.x * 256 + threadIdx.x;
    if (j >= 1276) return;
    float s = 0.f;
    for (int i = 0; i < 512; ++i) s += u527[10 + i] * seg_w[i*1276 + j];
    wsp[16 + j] = s;
}

// Build fragment-swizzled bf16 combined weights Wc and gate bias.
// Logical W: [n=1024][k=320], k<56: w_ih, 56<=k<64: 0 (pad), k>=64: w_hh[k-64].
// Physical: elem for (ntile=n>>4, kk=k>>5) at ((ntile*10+kk)*64 + lane)*8 + e
// with n = ntile*16 + (lane&15), k = kk*32 + (lane>>4)*8 + e.
__global__ void k_wc(const float* __restrict__ w_ih, const float* __restrict__ b_ih,
                     const float* __restrict__ w_hh, const float* __restrict__ b_hh,
                     bf16_t* __restrict__ wc, float* __restrict__ biasg) {
    int idx = blockIdx.x * 256 + threadIdx.x;
    if (idx < 1024) biasg[idx] = b_ih[idx] + b_hh[idx];
    if (idx < 1024 * 320) {
        int e  = idx & 7;
        int l  = (idx >> 3) & 63;
        int t2 = idx >> 9;
        int kk = t2 % 10;
        int nt = t2 / 10;
        int n  = nt * 16 + (l & 15);
        int k  = kk * 32 + ((l >> 4) << 3) + e;
        float v = 0.f;
        if (k < 56)       v = w_ih[n*56 + k];
        else if (k >= 64) v = w_hh[n*256 + (k - 64)];
        wc[idx] = (bf16_t)v;
    }
}

// out[b] = dot(spatial[b], w_sp) + bias   (one wave per row)
__global__ void k_spatial(const float* __restrict__ sp, const float* __restrict__ wsp,
                          const float* __restrict__ bias, float* __restrict__ out) {
    int row  = blockIdx.x * 4 + (threadIdx.x >> 6);
    int lane = threadIdx.x & 63;
    const float* rp = sp + (size_t)row * 1297;
    float s = 0.f;
    for (int k = lane; k < 1297; k += 64) s += rp[k] * wsp[k];
    s += __shfl_xor(s, 1);  s += __shfl_xor(s, 2);  s += __shfl_xor(s, 4);
    s += __shfl_xor(s, 8);  s += __shfl_xor(s, 16); s += __shfl_xor(s, 32);
    if (lane == 0) out[row] = s + bias[0];
}

// ---------------- LSTM: weight-stationary, 256 blocks x 64 rows, 16 waves ----------------
// A-tile (LDS): [64 rows][328 bf16], cols 0..55 = x_t, 56..63 = 0, 64..319 = h.
// Wave w owns hidden dims [16w,16w+16) for ALL 4 gates (gate coupling wave-local).
// Weights (40 x f32x4 = 160 VGPR) are loaded ONCE and pinned via asm so the
// compiler cannot rematerialize the global loads inside the t-loop.
// __launch_bounds__(1024, 4): 4 waves/EU -> VGPR cap 512, room for ~290 live.
__launch_bounds__(1024, 4)
__global__ void k_lstm(const float* __restrict__ temporal, const bf16_t* __restrict__ wc,
                       const float* __restrict__ biasg, const float* __restrict__ ah,
                       float* __restrict__ out) {
    __shared__ bf16_t At[64 * 328];
    const int tid  = threadIdx.x;
    const int lane = tid & 63;
    const int w    = tid >> 6;              // wave 0..15
    const int row0 = blockIdx.x * 64;
    const int l15  = lane & 15;
    const int l4q  = lane >> 4;             // 0..3

    // --- persistent weight fragments: wfr[q][kk] for gate q, K-chunk kk ---
    f32x4 wfr[4][10];
#pragma unroll
    for (int q = 0; q < 4; ++q)
#pragma unroll
        for (int kk = 0; kk < 10; ++kk) {
            int ntg = q * 16 + w;           // global n-tile (col q*256 + 16w)
            wfr[q][kk] = *reinterpret_cast<const f32x4*>(
                wc + (((size_t)(ntg * 10 + kk) * 64 + lane) * 8));
        }
    // Pin: make values opaque -> no rematerialization of the loads.
#pragma unroll
    for (int q = 0; q < 4; ++q)
#pragma unroll
        for (int kk = 0; kk < 10; ++kk)
            asm volatile("" : "+v"(wfr[q][kk]));

    float bias[4];
#pragma unroll
    for (int q = 0; q < 4; ++q) bias[q] = biasg[q*256 + w*16 + l15];

    f32x4 cst[4];
#pragma unroll
    for (int rt = 0; rt < 4; ++rt) cst[rt] = (f32x4){0.f, 0.f, 0.f, 0.f};

    for (int i = tid; i < 64 * 328; i += 1024) At[i] = (bf16_t)0.f;
    __syncthreads();

    int aoff[4];
#pragma unroll
    for (int rt = 0; rt < 4; ++rt) aoff[rt] = (16*rt + l15) * 328 + l4q * 8;

    const float* xbase = temporal + (size_t)row0 * (96 * 56);
    const int hcol = 64 + w*16 + l15;

    for (int t = 0; t < 96; ++t) {
        // stage x_t into A cols [0,56)
        for (int i = tid; i < 64 * 56; i += 1024) {
            int r = i / 56, c = i - r * 56;
            At[r*328 + c] = (bf16_t)xbase[(size_t)r * (96*56) + t*56 + c];
        }
        __syncthreads();   // x + previous h visible to all

        f32x4 acc[4][4];   // [rowtile][gate]
#pragma unroll
        for (int rt = 0; rt < 4; ++rt)
#pragma unroll
            for (int q = 0; q < 4; ++q)
                acc[rt][q] = (f32x4){bias[q], bias[q], bias[q], bias[q]};

#pragma unroll
        for (int kk = 0; kk < 10; ++kk) {
            bf16x8 af[4];
#pragma unroll
            for (int rt = 0; rt < 4; ++rt)
                af[rt] = *reinterpret_cast<const bf16x8*>(&At[aoff[rt] + kk*32]);
#pragma unroll
            for (int q = 0; q < 4; ++q)
#pragma unroll
                for (int rt = 0; rt < 4; ++rt)
                    acc[rt][q] = __builtin_amdgcn_mfma_f32_16x16x32_bf16(
                        af[rt], __builtin_bit_cast(bf16x8, wfr[q][kk]), acc[rt][q], 0, 0, 0);
        }
        __syncthreads();   // all A reads done before h (and next x) overwrite

        // gates -> c,h ; write h (bf16) back into A-tile cols [64,320)
#pragma unroll
        for (int rt = 0; rt < 4; ++rt)
#pragma unroll
            for (int reg = 0; reg < 4; ++reg) {
                float ig = sigmoidf_fast(acc[rt][0][reg]);
                float fg = sigmoidf_fast(acc[rt][1][reg]);
                float gt = tanhf_fast(acc[rt][2][reg]);
                float og = sigmoidf_fast(acc[rt][3][reg]);
                float cn = fg * cst[rt][reg] + ig * gt;
                cst[rt][reg] = cn;
                float hh = og * tanhf_fast(cn);
                At[(16*rt + l4q*4 + reg)*328 + hcol] = (bf16_t)hh;
            }
    }
    __syncthreads();

    // out[row] += ah . h_T[row]   (16 threads per row)
    {
        int r = tid >> 4, part = tid & 15;
        float s = 0.f;
#pragma unroll
        for (int j = 0; j < 16; ++j)
            s += ah[part*16 + j] * (float)At[r*328 + 64 + part*16 + j];
        s += __shfl_xor(s, 1); s += __shfl_xor(s, 2);
        s += __shfl_xor(s, 4); s += __shfl_xor(s, 8);
        if (part == 0) out[row0 + r] += s;
    }
}

// ---------------- launch ----------------
extern "C" void kernel_launch(void* const* d_in, const int* in_sizes, int n_in,
                              void* d_out, int out_size, void* d_ws, size_t ws_size,
                              hipStream_t stream) {
    const float* spatial  = (const float*)d_in[0];
    const float* temporal = (const float*)d_in[1];
    const float* sl_w = (const float*)d_in[2];  const float* sl_b = (const float*)d_in[3];
    const float* st_w = (const float*)d_in[4];  const float* st_b = (const float*)d_in[5];
    const float* seg_w = (const float*)d_in[6]; const float* seg_b = (const float*)d_in[7];
    const float* l1_w = (const float*)d_in[8];  const float* l1_b = (const float*)d_in[9];
    const float* l2_w = (const float*)d_in[10]; const float* l2_b = (const float*)d_in[11];
    const float* w_ih = (const float*)d_in[12]; const float* b_ih = (const float*)d_in[13];
    const float* w_hh = (const float*)d_in[14]; const float* b_hh = (const float*)d_in[15];
    const float* l4_w = (const float*)d_in[16]; const float* l4_b = (const float*)d_in[17];
    const float* l5_w = (const float*)d_in[18]; const float* l5_b = (const float*)d_in[19];
    const float* l6_w = (const float*)d_in[20]; const float* l6_b = (const float*)d_in[21];
    const float* l7_w = (const float*)d_in[22]; const float* l7_b = (const float*)d_in[23];

    char* ws = (char*)d_ws;
    float*  wsp   = (float*)(ws + WS_WSP);
    float*  ah    = (float*)(ws + WS_AH);
    float*  u527  = (float*)(ws + WS_U527);
    float*  biasT = (float*)(ws + WS_BIAS);
    float*  biasg = (float*)(ws + WS_BIASG);
    bf16_t* wc    = (bf16_t*)(ws + WS_WC);

    float* out = (float*)d_out;

    hipLaunchKernelGGL(k_head, dim3(1), dim3(512), 0, stream,
                       sl_w, sl_b, st_w, st_b, seg_b, l1_w, l1_b, l2_w, l2_b,
                       l4_w, l4_b, l5_w, l5_b, l6_w, l6_b, l7_w, l7_b,
                       wsp, ah, u527, biasT);
    hipLaunchKernelGGL(k_seg, dim3(5), dim3(256), 0, stream, seg_w, u527, wsp);
    hipLaunchKernelGGL(k_wc, dim3((1024*320 + 255)/256), dim3(256), 0, stream,
                       w_ih, b_ih, w_hh, b_hh, wc, biasg);
    hipLaunchKernelGGL(k_spatial, dim3(16384/4), dim3(256), 0, stream,
                       spatial, wsp, biasT, out);
    hipLaunchKernelGGL(k_lstm, dim3(256), dim3(1024), 0, stream,
                       temporal, wc, biasg, ah, out);
}